// Round 3
// baseline (2144.976 us; speedup 1.0000x reference)
//
#include <hip/hip_runtime.h>
#include <hip/hip_bf16.h>

#define NB 4
#define CB 64
#define HB 256
#define WB 256
#define OB 18
#define HWB (HB*WB)
#define TILE 16
#define EPSV 1e-5f

__device__ __forceinline__ int reflect_idx(int i, int n) {
    if (i < 0) i = -i;
    if (i >= n) i = 2*n - 2 - i;
    return i;
}

// Transpose weights (18,64,3,3) -> wt[c][o][k] (162 contiguous floats per input channel).
__global__ __launch_bounds__(256) void transpose_w_kernel(
    const float* __restrict__ w, float* __restrict__ wt)
{
    int i = blockIdx.x * 256 + threadIdx.x;
    if (i < OB*CB*9) {
        int o   = i / (CB*9);
        int rem = i - o*CB*9;
        int c   = rem / 9;
        int k   = rem - c*9;
        wt[c*OB*9 + o*9 + k] = w[i];
    }
}

// Kernel 1: 3x3x64->18 conv + per-block sum/sumsq partials.
// Weights live in LDS (in-order lgkmcnt -> pipelined broadcast reads).
// Halo staging double-buffered with register prefetch (1 barrier/chunk).
__global__ __launch_bounds__(256) void conv_stats_kernel(
    const float* __restrict__ y, const float* __restrict__ wt,
    float* __restrict__ sigma, float* __restrict__ psum, float* __restrict__ psq)
{
    __shared__ __align__(16) float lds_w[CB*164];   // padded stride: 164*4B=656, 16B-aligned
    __shared__ float halo[2][4*324];
    __shared__ float red[4][36];
    const int tid = threadIdx.x;
    const int tx = tid & 15, ty = tid >> 4;
    const int bx = blockIdx.x, by = blockIdx.y, n = blockIdx.z;
    const int h0 = by * TILE, w0 = bx * TILE;
    const float* ybase = y + (size_t)n*CB*HWB;

    // staging map for a 4-channel chunk (4*324 = 1296 = 5*256 + 16)
    int scc[6], soff[6];
#pragma unroll
    for (int i = 0; i < 6; ++i) {
        int j = tid + i*256;
        if (j < 1296) {
            int c   = j / 324;
            int rem = j - c*324;
            int r   = rem / 18;
            int col = rem - r*18;
            scc[i]  = c;
            soff[i] = reflect_idx(h0 - 1 + r, HB)*WB + reflect_idx(w0 - 1 + col, WB);
        } else { scc[i] = 0; soff[i] = 0; }
    }

    // ---- prologue: stage weights -> LDS, prefetch chunk 0 ----
    float wreg[41];
#pragma unroll
    for (int r = 0; r < 40; ++r) wreg[r] = wt[tid + r*256];
    if (tid < 128) wreg[40] = wt[tid + 10240];

    float pf[6];
#pragma unroll
    for (int i = 0; i < 5; ++i) pf[i] = ybase[(size_t)scc[i]*HWB + soff[i]];
    if (tid < 16) pf[5] = ybase[(size_t)scc[5]*HWB + soff[5]];

#pragma unroll
    for (int r = 0; r < 40; ++r) {
        int i = tid + r*256;
        int c = i / 162;
        lds_w[c*164 + (i - c*162)] = wreg[r];
    }
    if (tid < 128) {
        int i = tid + 10240;
        int c = i / 162;
        lds_w[c*164 + (i - c*162)] = wreg[40];
    }
#pragma unroll
    for (int i = 0; i < 5; ++i) halo[0][tid + i*256] = pf[i];
    if (tid < 16) halo[0][tid + 1280] = pf[5];

    float acc[OB];
#pragma unroll
    for (int o = 0; o < OB; ++o) acc[o] = 0.f;

    // ---- main loop: 16 chunks of 4 channels, double-buffered ----
    for (int k = 0; k < 16; ++k) {
        const int cb = k*4;
        float npf[6];
        if (k < 15) {
#pragma unroll
            for (int i = 0; i < 5; ++i)
                npf[i] = ybase[(size_t)(cb + 4 + scc[i])*HWB + soff[i]];
            if (tid < 16) npf[5] = ybase[(size_t)(cb + 4 + scc[5])*HWB + soff[5]];
        }
        __syncthreads();
        const float* hp = halo[k & 1];
#pragma unroll
        for (int ii = 0; ii < 4; ++ii) {
            float v[9];
#pragma unroll
            for (int dy = 0; dy < 3; ++dy)
#pragma unroll
                for (int dx = 0; dx < 3; ++dx)
                    v[dy*3+dx] = hp[ii*324 + (ty+dy)*18 + tx+dx];
            const float* wch = lds_w + (cb + ii)*164;
#pragma unroll
            for (int f = 0; f < 40; ++f) {
                float4 wv = *(const float4*)(wch + f*4);   // ds_read_b128 broadcast
                const int j0 = f*4;
                acc[(j0+0)/9] = fmaf(v[(j0+0)%9], wv.x, acc[(j0+0)/9]);
                acc[(j0+1)/9] = fmaf(v[(j0+1)%9], wv.y, acc[(j0+1)/9]);
                acc[(j0+2)/9] = fmaf(v[(j0+2)%9], wv.z, acc[(j0+2)/9]);
                acc[(j0+3)/9] = fmaf(v[(j0+3)%9], wv.w, acc[(j0+3)/9]);
            }
            float2 w2 = *(const float2*)(wch + 160);
            acc[17] = fmaf(v[7], w2.x, acc[17]);
            acc[17] = fmaf(v[8], w2.y, acc[17]);
        }
        if (k < 15) {
            float* hn = halo[(k + 1) & 1];
#pragma unroll
            for (int i = 0; i < 5; ++i) hn[tid + i*256] = npf[i];
            if (tid < 16) hn[tid + 1280] = npf[5];
        }
    }

    const int q = (h0 + ty)*WB + (w0 + tx);
#pragma unroll
    for (int o = 0; o < OB; ++o)
        sigma[((size_t)n*OB + o)*HWB + q] = acc[o];

    const int lane = tid & 63, wv = tid >> 6;
#pragma unroll
    for (int o = 0; o < OB; ++o) {
        float s  = acc[o];
        float s2 = acc[o]*acc[o];
        for (int off = 32; off > 0; off >>= 1) {
            s  += __shfl_down(s,  off, 64);
            s2 += __shfl_down(s2, off, 64);
        }
        if (lane == 0) { red[wv][o] = s; red[wv][o + OB] = s2; }
    }
    __syncthreads();
    if (tid < 36) {
        float t = red[0][tid] + red[1][tid] + red[2][tid] + red[3][tid];
        const int bid = (n*16 + by)*16 + bx;
        if (tid < OB) psum[tid*1024 + bid] = t;
        else          psq[(tid-OB)*1024 + bid] = t;
    }
}

// Kernel 2: reduce 1024 partials per channel -> fused scale/shift
__global__ __launch_bounds__(256) void stats_kernel(
    const float* __restrict__ psum, const float* __restrict__ psq,
    const float* __restrict__ gamma, const float* __restrict__ beta,
    float* __restrict__ scale, float* __restrict__ shift)
{
    const int o = blockIdx.x;
    const int t = threadIdx.x;
    float s = 0.f, s2 = 0.f;
#pragma unroll
    for (int i = 0; i < 4; ++i) {
        s  += psum[o*1024 + t + i*256];
        s2 += psq [o*1024 + t + i*256];
    }
    for (int off = 32; off > 0; off >>= 1) {
        s  += __shfl_down(s,  off, 64);
        s2 += __shfl_down(s2, off, 64);
    }
    __shared__ float red[8];
    const int lane = t & 63, wv = t >> 6;
    if (lane == 0) { red[wv] = s; red[wv + 4] = s2; }
    __syncthreads();
    if (t == 0) {
        float S  = red[0] + red[1] + red[2] + red[3];
        float SS = red[4] + red[5] + red[6] + red[7];
        const float cnt = (float)(NB * HWB);
        float mean = S / cnt;
        float var  = SS / cnt - mean*mean;
        float sc = gamma[o] * rsqrtf(var + EPSV);
        scale[o] = sc;
        shift[o] = beta[o] - mean * sc;
    }
}

// Kernel 3: softmax over 18 + adaptive filter, double-buffered staging.
__global__ __launch_bounds__(256) void softmax_apply_kernel(
    const float* __restrict__ y, const float* __restrict__ sigma,
    const float* __restrict__ scale, const float* __restrict__ shift,
    float* __restrict__ out)
{
    __shared__ float halo[2][8*324];   // 2 x 10368 B
    const int tid = threadIdx.x;
    const int tx = tid & 15, ty = tid >> 4;
    const int bx = blockIdx.x, by = blockIdx.y, n = blockIdx.z;
    const int h0 = by * TILE, w0 = bx * TILE;
    const int q = (h0 + ty)*WB + (w0 + tx);
    const float* ybase = y + (size_t)n*CB*HWB;
    float* obase = out + (size_t)n*CB*HWB;

    // staging map for an 8-channel chunk (8*324 = 2592 = 10*256 + 32)
    int scc[11], soff[11];
#pragma unroll
    for (int i = 0; i < 11; ++i) {
        int j = tid + i*256;
        if (j < 2592) {
            int c   = j / 324;
            int rem = j - c*324;
            int r   = rem / 18;
            int col = rem - r*18;
            scc[i]  = c;
            soff[i] = reflect_idx(h0 - 1 + r, HB)*WB + reflect_idx(w0 - 1 + col, WB);
        } else { scc[i] = 0; soff[i] = 0; }
    }

    // issue sigma loads + chunk-0 prefetch, then softmax while they fly
    float z[OB];
#pragma unroll
    for (int o = 0; o < OB; ++o)
        z[o] = sigma[((size_t)n*OB + o)*HWB + q];

    float pf[11];
#pragma unroll
    for (int i = 0; i < 10; ++i) pf[i] = ybase[(size_t)scc[i]*HWB + soff[i]];
    if (tid < 32) pf[10] = ybase[(size_t)scc[10]*HWB + soff[10]];

#pragma unroll
    for (int o = 0; o < OB; ++o) z[o] = fmaf(z[o], scale[o], shift[o]);
    float m = z[0];
#pragma unroll
    for (int o = 1; o < OB; ++o) m = fmaxf(m, z[o]);
    float sum = 0.f;
#pragma unroll
    for (int o = 0; o < OB; ++o) { z[o] = __expf(z[o] - m); sum += z[o]; }
    const float r = 1.f / sum;

    float* vmap = out + (size_t)NB*CB*HWB;
#pragma unroll
    for (int o = 0; o < OB; ++o) {
        z[o] *= r;
        vmap[((size_t)n*OB + o)*HWB + q] = z[o];
    }

#pragma unroll
    for (int i = 0; i < 10; ++i) halo[0][tid + i*256] = pf[i];
    if (tid < 32) halo[0][tid + 2560] = pf[10];

#pragma unroll
    for (int k = 0; k < 8; ++k) {
        const int cb = k*8;
        float npf[11];
        if (k < 7) {
#pragma unroll
            for (int i = 0; i < 10; ++i)
                npf[i] = ybase[(size_t)(cb + 8 + scc[i])*HWB + soff[i]];
            if (tid < 32) npf[10] = ybase[(size_t)(cb + 8 + scc[10])*HWB + soff[10]];
        }
        __syncthreads();
        const float* hp = halo[k & 1];
#pragma unroll
        for (int ii = 0; ii < 8; ++ii) {
            const int c = cb + ii;            // compile-time (k, ii unrolled)
            const int g = c >> 5;             // compile-time -> z[] indices constant
            float a = 0.f;
#pragma unroll
            for (int dy = 0; dy < 3; ++dy)
#pragma unroll
                for (int dx = 0; dx < 3; ++dx)
                    a = fmaf(hp[ii*324 + (ty+dy)*18 + tx+dx], z[g*9 + dy*3 + dx], a);
            obase[(size_t)c*HWB + q] = a;
        }
        if (k < 7) {
            float* hn = halo[(k + 1) & 1];
#pragma unroll
            for (int i = 0; i < 10; ++i) hn[tid + i*256] = npf[i];
            if (tid < 32) hn[tid + 2560] = npf[10];
        }
    }
}

extern "C" void kernel_launch(void* const* d_in, const int* in_sizes, int n_in,
                              void* d_out, int out_size, void* d_ws, size_t ws_size,
                              hipStream_t stream) {
    const float* y     = (const float*)d_in[0];
    const float* w     = (const float*)d_in[1];
    const float* gamma = (const float*)d_in[2];
    const float* beta  = (const float*)d_in[3];
    float* out = (float*)d_out;

    float* sigma = (float*)d_ws;                 // 4*18*65536 floats
    float* wt    = sigma + (size_t)NB*OB*HWB;    // 10368
    float* psum  = wt + OB*CB*9;                 // 18*1024
    float* psq   = psum + OB*1024;               // 18*1024
    float* scale = psq  + OB*1024;               // 18
    float* shift = scale + OB;                   // 18

    dim3 grid(WB/TILE, HB/TILE, NB);   // (16,16,4)
    dim3 block(256);
    transpose_w_kernel<<<dim3((OB*CB*9 + 255)/256), block, 0, stream>>>(w, wt);
    conv_stats_kernel<<<grid, block, 0, stream>>>(y, wt, sigma, psum, psq);
    stats_kernel<<<dim3(OB), block, 0, stream>>>(psum, psq, gamma, beta, scale, shift);
    softmax_apply_kernel<<<grid, block, 0, stream>>>(y, sigma, scale, shift, out);
}

// Round 4
// 2112.220 us; speedup vs baseline: 1.0155x; 1.0155x over previous
//
#include <hip/hip_runtime.h>
#include <hip/hip_bf16.h>

#define NB 4
#define CB 64
#define HB 256
#define WB 256
#define OB 18
#define HWB (HB*WB)
#define TILE 16
#define EPSV 1e-5f

__device__ __forceinline__ int reflect_idx(int i, int n) {
    if (i < 0) i = -i;
    if (i >= n) i = 2*n - 2 - i;
    return i;
}

// Transpose weights (18,64,3,3) -> wt[c][o][k] (162 contiguous floats per input channel).
__global__ __launch_bounds__(256) void transpose_w_kernel(
    const float* __restrict__ w, float* __restrict__ wt)
{
    int i = blockIdx.x * 256 + threadIdx.x;
    if (i < OB*CB*9) {
        int o   = i / (CB*9);
        int rem = i - o*CB*9;
        int c   = rem / 9;
        int k   = rem - c*9;
        wt[c*OB*9 + o*9 + k] = w[i];
    }
}

// Kernel 1: 3x3x64->18 conv + per-block sum/sumsq partials.
// Weights in LDS (padded stride 164 -> 16B-aligned ds_read_b128 broadcasts,
// in-order lgkmcnt pipelines under the FMAs). Halo double-buffered with a
// SMALL register prefetch (6 regs); weight staging is a bounded-unroll
// streaming loop so VGPR stays ~80 (round 3's wreg[41] block spilled).
__global__ __launch_bounds__(256) void conv_stats_kernel(
    const float* __restrict__ y, const float* __restrict__ wt,
    float* __restrict__ sigma, float* __restrict__ psum, float* __restrict__ psq)
{
    __shared__ __align__(16) float lds_w[CB*164];   // 41984 B
    __shared__ float halo[2][4*324];                // 10368 B
    __shared__ float red[4][36];
    const int tid = threadIdx.x;
    const int tx = tid & 15, ty = tid >> 4;
    const int bx = blockIdx.x, by = blockIdx.y, n = blockIdx.z;
    const int h0 = by * TILE, w0 = bx * TILE;
    const float* ybase = y + (size_t)n*CB*HWB;

    // staging map for a 4-channel chunk (4*324 = 1296 = 5*256 + 16)
    int scc[6], soff[6];
#pragma unroll
    for (int i = 0; i < 6; ++i) {
        int j = tid + i*256;
        if (j < 1296) {
            int c   = j / 324;
            int rem = j - c*324;
            int r   = rem / 18;
            int col = rem - r*18;
            scc[i]  = c;
            soff[i] = reflect_idx(h0 - 1 + r, HB)*WB + reflect_idx(w0 - 1 + col, WB);
        } else { scc[i] = 0; soff[i] = 0; }
    }

    // ---- prologue: prefetch chunk 0, stream weights -> LDS ----
    float pf[6];
#pragma unroll
    for (int i = 0; i < 5; ++i) pf[i] = ybase[(size_t)scc[i]*HWB + soff[i]];
    if (tid < 16) pf[5] = ybase[(size_t)scc[5]*HWB + soff[5]];

#pragma unroll 4
    for (int i = tid; i < OB*CB*9; i += 256) {
        int c = i / 162;
        lds_w[c*164 + (i - c*162)] = wt[i];
    }

#pragma unroll
    for (int i = 0; i < 5; ++i) halo[0][tid + i*256] = pf[i];
    if (tid < 16) halo[0][tid + 1280] = pf[5];

    float acc[OB];
#pragma unroll
    for (int o = 0; o < OB; ++o) acc[o] = 0.f;

    // ---- main loop: 16 chunks of 4 channels, double-buffered ----
    for (int k = 0; k < 16; ++k) {
        const int cb = k*4;
        float npf[6];
        if (k < 15) {
#pragma unroll
            for (int i = 0; i < 5; ++i)
                npf[i] = ybase[(size_t)(cb + 4 + scc[i])*HWB + soff[i]];
            if (tid < 16) npf[5] = ybase[(size_t)(cb + 4 + scc[5])*HWB + soff[5]];
        }
        __syncthreads();
        const float* hp = halo[k & 1];
#pragma unroll
        for (int ii = 0; ii < 4; ++ii) {
            float v[9];
#pragma unroll
            for (int dy = 0; dy < 3; ++dy)
#pragma unroll
                for (int dx = 0; dx < 3; ++dx)
                    v[dy*3+dx] = hp[ii*324 + (ty+dy)*18 + tx+dx];
            const float* wch = lds_w + (cb + ii)*164;
#pragma unroll
            for (int f = 0; f < 40; ++f) {
                float4 wv = *(const float4*)(wch + f*4);   // b128 broadcast
                const int j0 = f*4;
                acc[(j0+0)/9] = fmaf(v[(j0+0)%9], wv.x, acc[(j0+0)/9]);
                acc[(j0+1)/9] = fmaf(v[(j0+1)%9], wv.y, acc[(j0+1)/9]);
                acc[(j0+2)/9] = fmaf(v[(j0+2)%9], wv.z, acc[(j0+2)/9]);
                acc[(j0+3)/9] = fmaf(v[(j0+3)%9], wv.w, acc[(j0+3)/9]);
            }
            float2 w2 = *(const float2*)(wch + 160);
            acc[17] = fmaf(v[7], w2.x, acc[17]);
            acc[17] = fmaf(v[8], w2.y, acc[17]);
        }
        if (k < 15) {
            float* hn = halo[(k + 1) & 1];
#pragma unroll
            for (int i = 0; i < 5; ++i) hn[tid + i*256] = npf[i];
            if (tid < 16) hn[tid + 1280] = npf[5];
        }
    }

    const int q = (h0 + ty)*WB + (w0 + tx);
#pragma unroll
    for (int o = 0; o < OB; ++o)
        sigma[((size_t)n*OB + o)*HWB + q] = acc[o];

    const int lane = tid & 63, wv = tid >> 6;
#pragma unroll
    for (int o = 0; o < OB; ++o) {
        float s  = acc[o];
        float s2 = acc[o]*acc[o];
        for (int off = 32; off > 0; off >>= 1) {
            s  += __shfl_down(s,  off, 64);
            s2 += __shfl_down(s2, off, 64);
        }
        if (lane == 0) { red[wv][o] = s; red[wv][o + OB] = s2; }
    }
    __syncthreads();
    if (tid < 36) {
        float t = red[0][tid] + red[1][tid] + red[2][tid] + red[3][tid];
        const int bid = (n*16 + by)*16 + bx;
        if (tid < OB) psum[tid*1024 + bid] = t;
        else          psq[(tid-OB)*1024 + bid] = t;
    }
}

// Kernel 2: reduce 1024 partials per channel -> fused scale/shift
__global__ __launch_bounds__(256) void stats_kernel(
    const float* __restrict__ psum, const float* __restrict__ psq,
    const float* __restrict__ gamma, const float* __restrict__ beta,
    float* __restrict__ scale, float* __restrict__ shift)
{
    const int o = blockIdx.x;
    const int t = threadIdx.x;
    float s = 0.f, s2 = 0.f;
#pragma unroll
    for (int i = 0; i < 4; ++i) {
        s  += psum[o*1024 + t + i*256];
        s2 += psq [o*1024 + t + i*256];
    }
    for (int off = 32; off > 0; off >>= 1) {
        s  += __shfl_down(s,  off, 64);
        s2 += __shfl_down(s2, off, 64);
    }
    __shared__ float red[8];
    const int lane = t & 63, wv = t >> 6;
    if (lane == 0) { red[wv] = s; red[wv + 4] = s2; }
    __syncthreads();
    if (t == 0) {
        float S  = red[0] + red[1] + red[2] + red[3];
        float SS = red[4] + red[5] + red[6] + red[7];
        const float cnt = (float)(NB * HWB);
        float mean = S / cnt;
        float var  = SS / cnt - mean*mean;
        float sc = gamma[o] * rsqrtf(var + EPSV);
        scale[o] = sc;
        shift[o] = beta[o] - mean * sc;
    }
}

// Kernel 3: softmax over 18 + adaptive filter, double-buffered staging.
__global__ __launch_bounds__(256) void softmax_apply_kernel(
    const float* __restrict__ y, const float* __restrict__ sigma,
    const float* __restrict__ scale, const float* __restrict__ shift,
    float* __restrict__ out)
{
    __shared__ float halo[2][8*324];   // 2 x 10368 B
    const int tid = threadIdx.x;
    const int tx = tid & 15, ty = tid >> 4;
    const int bx = blockIdx.x, by = blockIdx.y, n = blockIdx.z;
    const int h0 = by * TILE, w0 = bx * TILE;
    const int q = (h0 + ty)*WB + (w0 + tx);
    const float* ybase = y + (size_t)n*CB*HWB;
    float* obase = out + (size_t)n*CB*HWB;

    // staging map for an 8-channel chunk (8*324 = 2592 = 10*256 + 32)
    int scc[11], soff[11];
#pragma unroll
    for (int i = 0; i < 11; ++i) {
        int j = tid + i*256;
        if (j < 2592) {
            int c   = j / 324;
            int rem = j - c*324;
            int r   = rem / 18;
            int col = rem - r*18;
            scc[i]  = c;
            soff[i] = reflect_idx(h0 - 1 + r, HB)*WB + reflect_idx(w0 - 1 + col, WB);
        } else { scc[i] = 0; soff[i] = 0; }
    }

    // issue sigma loads + chunk-0 prefetch, then softmax while they fly
    float z[OB];
#pragma unroll
    for (int o = 0; o < OB; ++o)
        z[o] = sigma[((size_t)n*OB + o)*HWB + q];

    float pf[11];
#pragma unroll
    for (int i = 0; i < 10; ++i) pf[i] = ybase[(size_t)scc[i]*HWB + soff[i]];
    if (tid < 32) pf[10] = ybase[(size_t)scc[10]*HWB + soff[10]];

#pragma unroll
    for (int o = 0; o < OB; ++o) z[o] = fmaf(z[o], scale[o], shift[o]);
    float m = z[0];
#pragma unroll
    for (int o = 1; o < OB; ++o) m = fmaxf(m, z[o]);
    float sum = 0.f;
#pragma unroll
    for (int o = 0; o < OB; ++o) { z[o] = __expf(z[o] - m); sum += z[o]; }
    const float r = 1.f / sum;

    float* vmap = out + (size_t)NB*CB*HWB;
#pragma unroll
    for (int o = 0; o < OB; ++o) {
        z[o] *= r;
        vmap[((size_t)n*OB + o)*HWB + q] = z[o];
    }

#pragma unroll
    for (int i = 0; i < 10; ++i) halo[0][tid + i*256] = pf[i];
    if (tid < 32) halo[0][tid + 2560] = pf[10];

#pragma unroll
    for (int k = 0; k < 8; ++k) {
        const int cb = k*8;
        float npf[11];
        if (k < 7) {
#pragma unroll
            for (int i = 0; i < 10; ++i)
                npf[i] = ybase[(size_t)(cb + 8 + scc[i])*HWB + soff[i]];
            if (tid < 32) npf[10] = ybase[(size_t)(cb + 8 + scc[10])*HWB + soff[10]];
        }
        __syncthreads();
        const float* hp = halo[k & 1];
#pragma unroll
        for (int ii = 0; ii < 8; ++ii) {
            const int c = cb + ii;            // compile-time (k, ii unrolled)
            const int g = c >> 5;             // compile-time -> z[] indices constant
            float a = 0.f;
#pragma unroll
            for (int dy = 0; dy < 3; ++dy)
#pragma unroll
                for (int dx = 0; dx < 3; ++dx)
                    a = fmaf(hp[ii*324 + (ty+dy)*18 + tx+dx], z[g*9 + dy*3 + dx], a);
            obase[(size_t)c*HWB + q] = a;
        }
        if (k < 7) {
            float* hn = halo[(k + 1) & 1];
#pragma unroll
            for (int i = 0; i < 10; ++i) hn[tid + i*256] = npf[i];
            if (tid < 32) hn[tid + 2560] = npf[10];
        }
    }
}

extern "C" void kernel_launch(void* const* d_in, const int* in_sizes, int n_in,
                              void* d_out, int out_size, void* d_ws, size_t ws_size,
                              hipStream_t stream) {
    const float* y     = (const float*)d_in[0];
    const float* w     = (const float*)d_in[1];
    const float* gamma = (const float*)d_in[2];
    const float* beta  = (const float*)d_in[3];
    float* out = (float*)d_out;

    float* sigma = (float*)d_ws;                 // 4*18*65536 floats
    float* wt    = sigma + (size_t)NB*OB*HWB;    // 10368
    float* psum  = wt + OB*CB*9;                 // 18*1024
    float* psq   = psum + OB*1024;               // 18*1024
    float* scale = psq  + OB*1024;               // 18
    float* shift = scale + OB;                   // 18

    dim3 grid(WB/TILE, HB/TILE, NB);   // (16,16,4)
    dim3 block(256);
    transpose_w_kernel<<<dim3((OB*CB*9 + 255)/256), block, 0, stream>>>(w, wt);
    conv_stats_kernel<<<grid, block, 0, stream>>>(y, wt, sigma, psum, psq);
    stats_kernel<<<dim3(OB), block, 0, stream>>>(psum, psq, gamma, beta, scale, shift);
    softmax_apply_kernel<<<grid, block, 0, stream>>>(y, sigma, scale, shift, out);
}